// Round 6
// baseline (305.770 us; speedup 1.0000x reference)
//
#include <hip/hip_runtime.h>
#include <hip/hip_bf16.h>
#include <stdint.h>

#define NN 100000
#define NE 1600000
#define NF 128
#define NTILE ((NN + 63) / 64)      // 1563 row tiles of 64 (gemm)
#define GEMM_BLKS 512               // exactly one resident round (2 blocks/CU)
#define B_BKT 1563                  // 64-node buckets
#define NB2 128                     // binning blocks
#define EPB (NE / NB2)              // 12500 edges per binning block
#define NCNT (B_BKT * NB2)          // 200,064 segment counters
#define SC2A ((NCNT + 255) / 256)   // 782 scan blocks
#define CONV4 (NN * NF / 4)         // 3.2M float4 groups for convert
#define CONV_BLK ((CONV4 + 255) / 256)   // 12500
#define SETUP_GRID (NB2 + 16 + CONV_BLK) // count | prep | convert
#define CAP 3072                    // LDS edge buffer per bucket (avg 1024)

typedef __attribute__((ext_vector_type(8))) __bf16 bf16x8;
typedef __attribute__((ext_vector_type(4))) float floatx4;
typedef __attribute__((ext_vector_type(4))) unsigned short ushortx4;
typedef __attribute__((ext_vector_type(8))) unsigned short ushortx8;

static __device__ __forceinline__ unsigned short f2bf(float x) {
    union { float f; unsigned u; } v; v.f = x;
    unsigned r = v.u + 0x7fffu + ((v.u >> 16) & 1u);   // RNE
    return (unsigned short)(r >> 16);
}
static __device__ __forceinline__ float bflo(unsigned w) {
    union { unsigned u; float f; } v; v.u = w << 16; return v.f;
}
static __device__ __forceinline__ float bfhi(unsigned w) {
    union { unsigned u; float f; } v; v.u = w & 0xffff0000u; return v.f;
}

// Fused setup: blocks [0,NB2) histogram dst into 1563 fine buckets;
// blocks [NB2,NB2+16) build the swizzled W2t; the rest convert feat->bf16.
__global__ void k_setup(const float* __restrict__ feat, unsigned short* __restrict__ featb,
                        const float* __restrict__ wv, const float* __restrict__ wu,
                        unsigned short* __restrict__ w2t,
                        const int* __restrict__ dst, int* __restrict__ counts) {
    __shared__ int h[B_BKT];
    int b = blockIdx.x;
    int tid = threadIdx.x;
    if (b < NB2) {                       // ---- count ----
        for (int i = tid; i < B_BKT; i += 256) h[i] = 0;
        __syncthreads();
        int base = b * EPB, end = base + EPB;
        for (int i = base + tid; i < end; i += 256) {
            int d = __builtin_nontemporal_load(&dst[i]);
            atomicAdd(&h[d >> 6], 1);
        }
        __syncthreads();
        for (int i = tid; i < B_BKT; i += 256)
            counts[i * NB2 + b] = h[i];
    } else if (b < NB2 + 16) {           // ---- prep W2t ----
        int id = (b - NB2) * 256 + tid;  // 0..4095
        if (id < 128 * 32) {
            int n = id >> 5, kg = id & 31;
            const float* srcm = (kg < 16) ? wv : wu;
            int k0 = (kg & 15) * 8;
            ushortx8 o;
#pragma unroll
            for (int j = 0; j < 8; ++j)
                o[j] = f2bf(srcm[(k0 + j) * 128 + n]);
            int dchunk = n * 32 + (kg ^ (n & 7));
            *(ushortx8*)(w2t + dchunk * 8) = o;
        }
    } else {                             // ---- convert fp32 -> bf16 ----
        int i = (b - NB2 - 16) * 256 + tid;
        if (i < CONV4) {
            floatx4 f = __builtin_nontemporal_load((const floatx4*)feat + i);
            ushortx4 o;
            o.x = f2bf(f.x); o.y = f2bf(f.y); o.z = f2bf(f.z); o.w = f2bf(f.w);
            __builtin_nontemporal_store(o, (ushortx4*)featb + i);
        }
    }
}

// hierarchical exclusive scan of the 200,064 counts (bucket-major).
// counts[i] becomes block-local exclusive prefix; bsums[j] the block totals.
// Consumers add bsums[i>>8] on the fly.
__global__ void k_scan2_a(int* __restrict__ counts, int* __restrict__ bsums) {
    __shared__ int sh[256];
    int i = blockIdx.x * 256 + threadIdx.x;
    int v = (i < NCNT) ? counts[i] : 0;
    sh[threadIdx.x] = v;
    __syncthreads();
    for (int off = 1; off < 256; off <<= 1) {
        int u = (threadIdx.x >= off) ? sh[threadIdx.x - off] : 0;
        __syncthreads();
        sh[threadIdx.x] += u;
        __syncthreads();
    }
    if (i < NCNT) counts[i] = sh[threadIdx.x] - v;
    if (threadIdx.x == 255) bsums[blockIdx.x] = sh[255];
}
__global__ void k_scan2_b(int* __restrict__ bsums) {
    __shared__ int sh[1024];
    int t = threadIdx.x;
    int v = (t < SC2A) ? bsums[t] : 0;
    sh[t] = v;
    __syncthreads();
    for (int off = 1; off < 1024; off <<= 1) {
        int u = (t >= off) ? sh[t - off] : 0;
        __syncthreads();
        sh[t] += u;
        __syncthreads();
    }
    if (t < SC2A) bsums[t] = sh[t] - v;
}

// pass 2: deterministic scatter into bucket-sorted stream; LDS cursors only.
__global__ void k_binscatter(const int* __restrict__ src, const int* __restrict__ dst,
                             const int* __restrict__ counts, const int* __restrict__ bsums,
                             unsigned* __restrict__ streams) {
    __shared__ int cur[B_BKT];
    int tid = threadIdx.x;
    for (int i = tid; i < B_BKT; i += 512) {
        int idx = i * NB2 + blockIdx.x;
        cur[i] = counts[idx] + bsums[idx >> 8];
    }
    __syncthreads();
    int base = blockIdx.x * EPB, end = base + EPB;
    for (int i = base + tid; i < end; i += 512) {
        int d = __builtin_nontemporal_load(&dst[i]);
        int s = __builtin_nontemporal_load(&src[i]);
        int b = d >> 6;
        unsigned packed = ((unsigned)(d & 63) << 17) | (unsigned)s;
        int pos = atomicAdd(&cur[b], 1);
        streams[pos] = packed;
    }
}

// Fused CSR-finalize + aggregate: one block per 64-node bucket.
// Counting-sort the bucket's edge segment into a 12KB LDS buffer (hist ->
// nodeoff -> scatter; the re-read of streams is L2-hot), then run the proven
// shfl-broadcast gather (8 rows in flight) with edge IDs read from LDS.
// Deletes the k_csr kernel, the 6.4MB csr write+read, and the offs array.
__global__ void k_aggsort(const unsigned* __restrict__ streams,
                          const int* __restrict__ counts, const int* __restrict__ bsums,
                          const unsigned short* __restrict__ featb,
                          unsigned short* __restrict__ aggb) {
    __shared__ int hist[64];
    __shared__ int nodeoff[65];
    __shared__ int eb[CAP];
    int tid = threadIdx.x;
    int bkt = blockIdx.x;
    int idx = bkt * NB2;
    int s = counts[idx] + bsums[idx >> 8];
    int e = (bkt == B_BKT - 1) ? NE : (counts[idx + NB2] + bsums[(idx + NB2) >> 8]);
    int seg = e - s;
    int lane = tid & 63, wave = tid >> 6;

    if (tid < 64) hist[tid] = 0;
    __syncthreads();
    for (int i = s + tid; i < e; i += 256)
        atomicAdd(&hist[streams[i] >> 17], 1);
    __syncthreads();
    if (tid == 0) {
        int run = 0;
#pragma unroll
        for (int n = 0; n < 64; ++n) { nodeoff[n] = run; run += hist[n]; }
        nodeoff[64] = run;
    }
    __syncthreads();
    if (tid < 64) hist[tid] = nodeoff[tid];      // reuse as cursor
    __syncthreads();

    if (seg <= CAP) {
        for (int i = s + tid; i < e; i += 256) { // L2-hot second read
            unsigned v = streams[i];
            int p = atomicAdd(&hist[v >> 17], 1);
            eb[p] = (int)(v & 0x1FFFFu);
        }
        __syncthreads();
        // wave w aggregates nodes [w*16, w*16+16)
        for (int nl = wave * 16; nl < wave * 16 + 16; ++nl) {
            int node = bkt * 64 + nl;
            if (node >= NN) break;
            int s0 = nodeoff[nl], s1 = nodeoff[nl + 1];
            float a0 = 0.f, a1 = 0.f;
            for (int base = s0; base < s1; base += 64) {
                int ee = (base + lane < s1) ? eb[base + lane] : 0;
                int m = s1 - base; if (m > 64) m = 64;
                int j = 0;
                for (; j + 8 <= m; j += 8) {            // 8 loads in flight
                    unsigned w0 = *(const unsigned*)(featb + (size_t)__shfl(ee, j + 0, 64) * NF + lane * 2);
                    unsigned w1 = *(const unsigned*)(featb + (size_t)__shfl(ee, j + 1, 64) * NF + lane * 2);
                    unsigned w2 = *(const unsigned*)(featb + (size_t)__shfl(ee, j + 2, 64) * NF + lane * 2);
                    unsigned w3 = *(const unsigned*)(featb + (size_t)__shfl(ee, j + 3, 64) * NF + lane * 2);
                    unsigned w4 = *(const unsigned*)(featb + (size_t)__shfl(ee, j + 4, 64) * NF + lane * 2);
                    unsigned w5 = *(const unsigned*)(featb + (size_t)__shfl(ee, j + 5, 64) * NF + lane * 2);
                    unsigned w6 = *(const unsigned*)(featb + (size_t)__shfl(ee, j + 6, 64) * NF + lane * 2);
                    unsigned w7 = *(const unsigned*)(featb + (size_t)__shfl(ee, j + 7, 64) * NF + lane * 2);
                    a0 += bflo(w0) + bflo(w1) + bflo(w2) + bflo(w3)
                        + bflo(w4) + bflo(w5) + bflo(w6) + bflo(w7);
                    a1 += bfhi(w0) + bfhi(w1) + bfhi(w2) + bfhi(w3)
                        + bfhi(w4) + bfhi(w5) + bfhi(w6) + bfhi(w7);
                }
                for (; j < m; ++j) {
                    int nn = __shfl(ee, j, 64);
                    unsigned w = *(const unsigned*)(featb + (size_t)nn * NF + lane * 2);
                    a0 += bflo(w); a1 += bfhi(w);
                }
            }
            int dg = s1 - s0; if (dg < 1) dg = 1;
            float scale = 1.0f / (float)dg;
            unsigned outw = ((unsigned)f2bf(a1 * scale) << 16) | (unsigned)f2bf(a0 * scale);
            *(unsigned*)(aggb + (size_t)node * NF + lane * 2) = outw;
        }
    } else {
        // safety fallback (statistically unreachable: seg~Poisson(1024)):
        // per-node scan of the global segment, correct but slow.
        for (int nl = wave * 16; nl < wave * 16 + 16; ++nl) {
            int node = bkt * 64 + nl;
            if (node >= NN) break;
            float a0 = 0.f, a1 = 0.f;
            int dg = 0;
            for (int i = s; i < e; ++i) {
                unsigned v = streams[i];
                if ((int)(v >> 17) == nl) {
                    ++dg;
                    unsigned w = *(const unsigned*)(featb + (size_t)(v & 0x1FFFFu) * NF + lane * 2);
                    a0 += bflo(w); a1 += bfhi(w);
                }
            }
            int dc = dg < 1 ? 1 : dg;
            float scale = 1.0f / (float)dc;
            unsigned outw = ((unsigned)f2bf(a1 * scale) << 16) | (unsigned)f2bf(a0 * scale);
            *(unsigned*)(aggb + (size_t)node * NF + lane * 2) = outw;
        }
    }
}

// MFMA + epilogue, SWAPPED operands (verified correct in round 2):
// D[col][row] so each lane's 4 acc regs are 4 consecutive out-cols of its
// node row -> floatx4 (16B) stores; the 4 quads of a wave cover 64B runs and
// adjacent ct stores complete each 128B line back-to-back.
static __device__ __forceinline__ void gemm_tile_sw(
    const unsigned short* lds, const bf16x8* a, const float* __restrict__ bias,
    int rb, int quad, int l15, float* __restrict__ out) {
    floatx4 acc[8];
#pragma unroll
    for (int ct = 0; ct < 8; ++ct) acc[ct] = (floatx4){0.f, 0.f, 0.f, 0.f};
#pragma unroll
    for (int ct = 0; ct < 8; ++ct) {
        int n = ct * 16 + l15;
        int rowoff = n << 8;
        int sw = n & 7;
#pragma unroll
        for (int ks = 0; ks < 8; ++ks) {
            int kg = ks * 4 + quad;
            bf16x8 b = *(const bf16x8*)(&lds[rowoff + ((kg ^ sw) << 3)]);
            acc[ct] = __builtin_amdgcn_mfma_f32_16x16x32_bf16(b, a[ks], acc[ct], 0, 0, 0);
        }
    }
    int row = rb + l15;
    if (row < NN) {
        float* orow = out + (size_t)row * NF;
#pragma unroll
        for (int ct = 0; ct < 8; ++ct) {
            floatx4 bv = *(const floatx4*)(bias + ct * 16 + quad * 4);
            floatx4 v;
            v.x = acc[ct].x + bv.x; v.y = acc[ct].y + bv.y;
            v.z = acc[ct].z + bv.z; v.w = acc[ct].w + bv.w;
            v.x = v.x > 0.f ? v.x : 0.f;
            v.y = v.y > 0.f ? v.y : 0.f;
            v.z = v.z > 0.f ? v.z : 0.f;
            v.w = v.w > 0.f ? v.w : 0.f;
            *(floatx4*)(orow + ct * 16 + quad * 4) = v;
        }
    }
}

#define LOADA(A, rb)                                                          \
    {                                                                         \
        int ar = (rb) + l15; if (ar > NN - 1) ar = NN - 1;                    \
        const unsigned short* fr = featb + (size_t)ar * NF;                   \
        const unsigned short* ag = aggb + (size_t)ar * NF;                    \
        _Pragma("unroll")                                                     \
        for (int ks = 0; ks < 4; ++ks) {                                      \
            A[ks]     = *(const bf16x8*)(fr + ks * 32 + quad * 8);            \
            A[4 + ks] = *(const bf16x8*)(ag + ks * 32 + quad * 8);            \
        }                                                                     \
    }

// single fused GEMM: out = relu([feat | agg_n] @ W2 + bias), K=256.
// Grid = 512 = exactly one resident round (2 blocks/CU, 64KiB LDS) — kills
// the 782-block tail quantization (76% utilization). 3 tiles/block (+4th on
// 27 blocks), all three A-sets prefetched upfront: 24 loads in flight/wave.
__global__ __launch_bounds__(256, 2) void k_gemm(
    const unsigned short* __restrict__ featb,
    const unsigned short* __restrict__ aggb,
    const unsigned short* __restrict__ w2t,
    const float* __restrict__ bias,
    float* __restrict__ out) {
    __shared__ unsigned short lds[128 * 256];   // 64 KiB
    for (int i = threadIdx.x; i < 4096; i += 256) {
        ushortx8 w = *(const ushortx8*)(w2t + i * 8);
        *(ushortx8*)(&lds[i * 8]) = w;
    }
    __syncthreads();

    int lane = threadIdx.x & 63;
    int wave = threadIdx.x >> 6;
    int quad = lane >> 4, l15 = lane & 15;

    int t0 = blockIdx.x;
    int t1 = t0 + GEMM_BLKS, t2 = t0 + 2 * GEMM_BLKS, t3 = t0 + 3 * GEMM_BLKS;
    bool has3 = (t3 < NTILE);
    int rb0 = t0 * 64 + wave * 16;
    int rb1 = t1 * 64 + wave * 16;
    int rb2 = t2 * 64 + wave * 16;

    bf16x8 A0[8], A1[8], A2[8];
    LOADA(A0, rb0);
    LOADA(A1, rb1);
    LOADA(A2, rb2);

    gemm_tile_sw(lds, A0, bias, rb0, quad, l15, out);
    int rb3 = t3 * 64 + wave * 16;
    if (has3) LOADA(A0, rb3);
    gemm_tile_sw(lds, A1, bias, rb1, quad, l15, out);
    gemm_tile_sw(lds, A2, bias, rb2, quad, l15, out);
    if (has3)
        gemm_tile_sw(lds, A0, bias, rb3, quad, l15, out);
}

extern "C" void kernel_launch(void* const* d_in, const int* in_sizes, int n_in,
                              void* d_out, int out_size, void* d_ws, size_t ws_size,
                              hipStream_t stream) {
    const float* feat = (const float*)d_in[0];
    const float* wu   = (const float*)d_in[1];
    const float* wv   = (const float*)d_in[2];
    const float* bias = (const float*)d_in[3];
    const int* src    = (const int*)d_in[4];
    const int* dst    = (const int*)d_in[5];
    float* out        = (float*)d_out;

    char* ws = (char*)d_ws;
    int* counts           = (int*)(ws + 0);                    //   800,256 B
    int* bsums            = (int*)(ws + 800256);               //     4,096 B
    unsigned* streams     = (unsigned*)(ws + 1204480);         // 6,400,000 B (old csr slot)
    unsigned short* featb = (unsigned short*)(ws + 7604480);   // 25,600,000 B
    unsigned short* aggb  = (unsigned short*)(ws + 33204480);  // 25,600,000 B
    unsigned short* w2t   = (unsigned short*)(ws + 58804480);  //    65,536 B

    k_setup<<<SETUP_GRID, 256, 0, stream>>>(feat, featb, wv, wu, w2t, dst, counts);
    k_scan2_a<<<SC2A, 256, 0, stream>>>(counts, bsums);
    k_scan2_b<<<1, 1024, 0, stream>>>(bsums);
    k_binscatter<<<NB2, 512, 0, stream>>>(src, dst, counts, bsums, streams);
    k_aggsort<<<B_BKT, 256, 0, stream>>>(streams, counts, bsums, featb, aggb);
    k_gemm<<<GEMM_BLKS, 256, 0, stream>>>(featb, aggb, w2t, bias, out);
}

// Round 7
// 287.725 us; speedup vs baseline: 1.0627x; 1.0627x over previous
//
#include <hip/hip_runtime.h>
#include <hip/hip_bf16.h>
#include <stdint.h>

#define NN 100000
#define NE 1600000
#define NF 128
#define NTILE ((NN + 63) / 64)      // 1563 row tiles of 64 (gemm)
#define GEMM_G 782                  // gemm grid: each block does tiles t, t+782
#define B_BKT 1563                  // 64-node buckets
#define NB2 128                     // binning blocks
#define EPB (NE / NB2)              // 12500 edges per binning block
#define NCNT (B_BKT * NB2)          // 200,064 segment counters
#define SC2A ((NCNT + 255) / 256)   // 782 scan blocks
#define CONV4 (NN * NF / 4)         // 3.2M float4 groups for convert
#define CONV_BLK ((CONV4 + 255) / 256)   // 12500
#define SETUP_GRID (NB2 + 16 + CONV_BLK) // count | prep | convert
#define CAP 3072                    // LDS edge buffer per bucket (avg 1024)

typedef __attribute__((ext_vector_type(8))) __bf16 bf16x8;
typedef __attribute__((ext_vector_type(4))) float floatx4;
typedef __attribute__((ext_vector_type(4))) unsigned short ushortx4;
typedef __attribute__((ext_vector_type(8))) unsigned short ushortx8;

static __device__ __forceinline__ unsigned short f2bf(float x) {
    union { float f; unsigned u; } v; v.f = x;
    unsigned r = v.u + 0x7fffu + ((v.u >> 16) & 1u);   // RNE
    return (unsigned short)(r >> 16);
}
static __device__ __forceinline__ float bflo(unsigned w) {
    union { unsigned u; float f; } v; v.u = w << 16; return v.f;
}
static __device__ __forceinline__ float bfhi(unsigned w) {
    union { unsigned u; float f; } v; v.u = w & 0xffff0000u; return v.f;
}

// Fused setup: blocks [0,NB2) histogram dst into 1563 fine buckets;
// blocks [NB2,NB2+16) build the swizzled W2t; the rest convert feat->bf16.
__global__ void k_setup(const float* __restrict__ feat, unsigned short* __restrict__ featb,
                        const float* __restrict__ wv, const float* __restrict__ wu,
                        unsigned short* __restrict__ w2t,
                        const int* __restrict__ dst, int* __restrict__ counts) {
    __shared__ int h[B_BKT];
    int b = blockIdx.x;
    int tid = threadIdx.x;
    if (b < NB2) {                       // ---- count ----
        for (int i = tid; i < B_BKT; i += 256) h[i] = 0;
        __syncthreads();
        int base = b * EPB, end = base + EPB;
        for (int i = base + tid; i < end; i += 256) {
            int d = __builtin_nontemporal_load(&dst[i]);
            atomicAdd(&h[d >> 6], 1);
        }
        __syncthreads();
        for (int i = tid; i < B_BKT; i += 256)
            counts[i * NB2 + b] = h[i];
    } else if (b < NB2 + 16) {           // ---- prep W2t ----
        int id = (b - NB2) * 256 + tid;  // 0..4095
        if (id < 128 * 32) {
            int n = id >> 5, kg = id & 31;
            const float* srcm = (kg < 16) ? wv : wu;
            int k0 = (kg & 15) * 8;
            ushortx8 o;
#pragma unroll
            for (int j = 0; j < 8; ++j)
                o[j] = f2bf(srcm[(k0 + j) * 128 + n]);
            int dchunk = n * 32 + (kg ^ (n & 7));
            *(ushortx8*)(w2t + dchunk * 8) = o;
        }
    } else {                             // ---- convert fp32 -> bf16 ----
        int i = (b - NB2 - 16) * 256 + tid;
        if (i < CONV4) {
            floatx4 f = __builtin_nontemporal_load((const floatx4*)feat + i);
            ushortx4 o;
            o.x = f2bf(f.x); o.y = f2bf(f.y); o.z = f2bf(f.z); o.w = f2bf(f.w);
            __builtin_nontemporal_store(o, (ushortx4*)featb + i);
        }
    }
}

// hierarchical exclusive scan of the 200,064 counts (bucket-major).
__global__ void k_scan2_a(int* __restrict__ counts, int* __restrict__ bsums) {
    __shared__ int sh[256];
    int i = blockIdx.x * 256 + threadIdx.x;
    int v = (i < NCNT) ? counts[i] : 0;
    sh[threadIdx.x] = v;
    __syncthreads();
    for (int off = 1; off < 256; off <<= 1) {
        int u = (threadIdx.x >= off) ? sh[threadIdx.x - off] : 0;
        __syncthreads();
        sh[threadIdx.x] += u;
        __syncthreads();
    }
    if (i < NCNT) counts[i] = sh[threadIdx.x] - v;
    if (threadIdx.x == 255) bsums[blockIdx.x] = sh[255];
}
__global__ void k_scan2_b(int* __restrict__ bsums) {
    __shared__ int sh[1024];
    int t = threadIdx.x;
    int v = (t < SC2A) ? bsums[t] : 0;
    sh[t] = v;
    __syncthreads();
    for (int off = 1; off < 1024; off <<= 1) {
        int u = (t >= off) ? sh[t - off] : 0;
        __syncthreads();
        sh[t] += u;
        __syncthreads();
    }
    if (t < SC2A) bsums[t] = sh[t] - v;
}

// pass 2: deterministic scatter into bucket-sorted stream; LDS cursors only.
__global__ void k_binscatter(const int* __restrict__ src, const int* __restrict__ dst,
                             const int* __restrict__ counts, const int* __restrict__ bsums,
                             unsigned* __restrict__ streams) {
    __shared__ int cur[B_BKT];
    int tid = threadIdx.x;
    for (int i = tid; i < B_BKT; i += 512) {
        int idx = i * NB2 + blockIdx.x;
        cur[i] = counts[idx] + bsums[idx >> 8];
    }
    __syncthreads();
    int base = blockIdx.x * EPB, end = base + EPB;
    for (int i = base + tid; i < end; i += 512) {
        int d = __builtin_nontemporal_load(&dst[i]);
        int s = __builtin_nontemporal_load(&src[i]);
        int b = d >> 6;
        unsigned packed = ((unsigned)(d & 63) << 17) | (unsigned)s;
        int pos = atomicAdd(&cur[b], 1);
        streams[pos] = packed;
    }
}

// Fused CSR-finalize + aggregate: one block per 64-node bucket.
// Counting-sort the bucket's segment into LDS, then shfl-broadcast gather.
// Dynamic intra-block node queue (LDS cursor) removes wave imbalance.
__global__ void k_aggsort(const unsigned* __restrict__ streams,
                          const int* __restrict__ counts, const int* __restrict__ bsums,
                          const unsigned short* __restrict__ featb,
                          unsigned short* __restrict__ aggb) {
    __shared__ int hist[64];
    __shared__ int nodeoff[65];
    __shared__ int eb[CAP];
    __shared__ int nextn;
    int tid = threadIdx.x;
    int bkt = blockIdx.x;
    int idx = bkt * NB2;
    int s = counts[idx] + bsums[idx >> 8];
    int e = (bkt == B_BKT - 1) ? NE : (counts[idx + NB2] + bsums[(idx + NB2) >> 8]);
    int seg = e - s;
    int lane = tid & 63, wave = tid >> 6;

    if (tid < 64) hist[tid] = 0;
    if (tid == 0) nextn = 0;
    __syncthreads();
    for (int i = s + tid; i < e; i += 256)
        atomicAdd(&hist[streams[i] >> 17], 1);
    __syncthreads();
    if (tid == 0) {
        int run = 0;
#pragma unroll
        for (int n = 0; n < 64; ++n) { nodeoff[n] = run; run += hist[n]; }
        nodeoff[64] = run;
    }
    __syncthreads();
    if (tid < 64) hist[tid] = nodeoff[tid];      // reuse as cursor
    __syncthreads();

    if (seg <= CAP) {
        for (int i = s + tid; i < e; i += 256) { // L2-hot second read
            unsigned v = streams[i];
            int p = atomicAdd(&hist[v >> 17], 1);
            eb[p] = (int)(v & 0x1FFFFu);
        }
        __syncthreads();
        for (;;) {                               // dynamic node queue
            int nl;
            if (lane == 0) nl = atomicAdd(&nextn, 1);
            nl = __shfl(nl, 0, 64);
            if (nl >= 64) break;
            int node = bkt * 64 + nl;
            if (node >= NN) continue;
            int s0 = nodeoff[nl], s1 = nodeoff[nl + 1];
            float a0 = 0.f, a1 = 0.f;
            for (int base = s0; base < s1; base += 64) {
                int ee = (base + lane < s1) ? eb[base + lane] : 0;
                int m = s1 - base; if (m > 64) m = 64;
                int j = 0;
                for (; j + 8 <= m; j += 8) {            // 8 loads in flight
                    unsigned w0 = *(const unsigned*)(featb + (size_t)__shfl(ee, j + 0, 64) * NF + lane * 2);
                    unsigned w1 = *(const unsigned*)(featb + (size_t)__shfl(ee, j + 1, 64) * NF + lane * 2);
                    unsigned w2 = *(const unsigned*)(featb + (size_t)__shfl(ee, j + 2, 64) * NF + lane * 2);
                    unsigned w3 = *(const unsigned*)(featb + (size_t)__shfl(ee, j + 3, 64) * NF + lane * 2);
                    unsigned w4 = *(const unsigned*)(featb + (size_t)__shfl(ee, j + 4, 64) * NF + lane * 2);
                    unsigned w5 = *(const unsigned*)(featb + (size_t)__shfl(ee, j + 5, 64) * NF + lane * 2);
                    unsigned w6 = *(const unsigned*)(featb + (size_t)__shfl(ee, j + 6, 64) * NF + lane * 2);
                    unsigned w7 = *(const unsigned*)(featb + (size_t)__shfl(ee, j + 7, 64) * NF + lane * 2);
                    a0 += bflo(w0) + bflo(w1) + bflo(w2) + bflo(w3)
                        + bflo(w4) + bflo(w5) + bflo(w6) + bflo(w7);
                    a1 += bfhi(w0) + bfhi(w1) + bfhi(w2) + bfhi(w3)
                        + bfhi(w4) + bfhi(w5) + bfhi(w6) + bfhi(w7);
                }
                for (; j < m; ++j) {
                    int nn = __shfl(ee, j, 64);
                    unsigned w = *(const unsigned*)(featb + (size_t)nn * NF + lane * 2);
                    a0 += bflo(w); a1 += bfhi(w);
                }
            }
            int dg = s1 - s0; if (dg < 1) dg = 1;
            float scale = 1.0f / (float)dg;
            unsigned outw = ((unsigned)f2bf(a1 * scale) << 16) | (unsigned)f2bf(a0 * scale);
            *(unsigned*)(aggb + (size_t)node * NF + lane * 2) = outw;
        }
    } else {
        // safety fallback (statistically unreachable: seg~Poisson(1024)):
        for (int nl = wave * 16; nl < wave * 16 + 16; ++nl) {
            int node = bkt * 64 + nl;
            if (node >= NN) break;
            float a0 = 0.f, a1 = 0.f;
            int dg = 0;
            for (int i = s; i < e; ++i) {
                unsigned v = streams[i];
                if ((int)(v >> 17) == nl) {
                    ++dg;
                    unsigned w = *(const unsigned*)(featb + (size_t)(v & 0x1FFFFu) * NF + lane * 2);
                    a0 += bflo(w); a1 += bfhi(w);
                }
            }
            int dc = dg < 1 ? 1 : dg;
            float scale = 1.0f / (float)dc;
            unsigned outw = ((unsigned)f2bf(a1 * scale) << 16) | (unsigned)f2bf(a0 * scale);
            *(unsigned*)(aggb + (size_t)node * NF + lane * 2) = outw;
        }
    }
}

// MFMA + epilogue for one 64-row tile (A-fragments already loaded).
// Round-5 proven version — unswapped operands, scalar epilogue stores.
static __device__ __forceinline__ void gemm_tile(
    const unsigned short* lds, const bf16x8* a, const float* bsv,
    int rb, int quad, int l15, float* __restrict__ out) {
    floatx4 acc[8];
#pragma unroll
    for (int ct = 0; ct < 8; ++ct) acc[ct] = (floatx4){0.f, 0.f, 0.f, 0.f};
#pragma unroll
    for (int ct = 0; ct < 8; ++ct) {
        int n = ct * 16 + l15;
        int rowoff = n << 8;
        int sw = n & 7;
#pragma unroll
        for (int ks = 0; ks < 8; ++ks) {
            int kg = ks * 4 + quad;
            bf16x8 b = *(const bf16x8*)(&lds[rowoff + ((kg ^ sw) << 3)]);
            acc[ct] = __builtin_amdgcn_mfma_f32_16x16x32_bf16(a[ks], b, acc[ct], 0, 0, 0);
        }
    }
#pragma unroll
    for (int r = 0; r < 4; ++r) {
        int row = rb + quad * 4 + r;
        if (row < NN) {
#pragma unroll
            for (int ct = 0; ct < 8; ++ct) {
                int col = ct * 16 + l15;
                float v = acc[ct][r] + bsv[ct];
                out[(size_t)row * NF + col] = v > 0.f ? v : 0.f;
            }
        }
    }
}

// single fused GEMM: out = relu([feat | agg_n] @ W2 + bias), K=256.
// Round-5 proven composition: 256-thr blocks, 782 grid, two tiles per block
// (t, t+GEMM_G) with tile-2's A-loads issued before tile-1's MFMA.
__global__ __launch_bounds__(256, 2) void k_gemm(
    const unsigned short* __restrict__ featb,
    const unsigned short* __restrict__ aggb,
    const unsigned short* __restrict__ w2t,
    const float* __restrict__ bias,
    float* __restrict__ out) {
    __shared__ unsigned short lds[128 * 256];   // 64 KiB
    for (int i = threadIdx.x; i < 4096; i += 256) {
        ushortx8 w = *(const ushortx8*)(w2t + i * 8);
        *(ushortx8*)(&lds[i * 8]) = w;
    }
    __syncthreads();

    int lane = threadIdx.x & 63;
    int wave = threadIdx.x >> 6;
    int quad = lane >> 4, l15 = lane & 15;

    float bsv[8];
#pragma unroll
    for (int ct = 0; ct < 8; ++ct) bsv[ct] = bias[ct * 16 + l15];

    int t0 = blockIdx.x;
    int t1 = t0 + GEMM_G;                    // may be >= NTILE (last block)
    int t1v = (t1 < NTILE) ? t1 : t0;        // safe address for the prefetch

    int rb0 = t0 * 64 + wave * 16;
    int rb1 = t1v * 64 + wave * 16;
    int ar0 = rb0 + l15; if (ar0 > NN - 1) ar0 = NN - 1;
    int ar1 = rb1 + l15; if (ar1 > NN - 1) ar1 = NN - 1;
    const unsigned short* fr0 = featb + (size_t)ar0 * NF;
    const unsigned short* ag0 = aggb + (size_t)ar0 * NF;
    const unsigned short* fr1 = featb + (size_t)ar1 * NF;
    const unsigned short* ag1 = aggb + (size_t)ar1 * NF;

    bf16x8 a0[8], a1[8];
#pragma unroll
    for (int ks = 0; ks < 4; ++ks) {         // tile-1 A-fragments
        a0[ks]     = *(const bf16x8*)(fr0 + ks * 32 + quad * 8);
        a0[4 + ks] = *(const bf16x8*)(ag0 + ks * 32 + quad * 8);
    }
#pragma unroll
    for (int ks = 0; ks < 4; ++ks) {         // tile-2 prefetch, in flight
        a1[ks]     = *(const bf16x8*)(fr1 + ks * 32 + quad * 8);
        a1[4 + ks] = *(const bf16x8*)(ag1 + ks * 32 + quad * 8);
    }

    gemm_tile(lds, a0, bsv, rb0, quad, l15, out);
    if (t1 < NTILE)
        gemm_tile(lds, a1, bsv, rb1, quad, l15, out);
}

extern "C" void kernel_launch(void* const* d_in, const int* in_sizes, int n_in,
                              void* d_out, int out_size, void* d_ws, size_t ws_size,
                              hipStream_t stream) {
    const float* feat = (const float*)d_in[0];
    const float* wu   = (const float*)d_in[1];
    const float* wv   = (const float*)d_in[2];
    const float* bias = (const float*)d_in[3];
    const int* src    = (const int*)d_in[4];
    const int* dst    = (const int*)d_in[5];
    float* out        = (float*)d_out;

    char* ws = (char*)d_ws;
    int* counts           = (int*)(ws + 0);                    //   800,256 B
    int* bsums            = (int*)(ws + 800256);               //     4,096 B
    unsigned* streams     = (unsigned*)(ws + 1204480);         // 6,400,000 B
    unsigned short* featb = (unsigned short*)(ws + 7604480);   // 25,600,000 B
    unsigned short* aggb  = (unsigned short*)(ws + 33204480);  // 25,600,000 B
    unsigned short* w2t   = (unsigned short*)(ws + 58804480);  //    65,536 B

    k_setup<<<SETUP_GRID, 256, 0, stream>>>(feat, featb, wv, wu, w2t, dst, counts);
    k_scan2_a<<<SC2A, 256, 0, stream>>>(counts, bsums);
    k_scan2_b<<<1, 1024, 0, stream>>>(bsums);
    k_binscatter<<<NB2, 512, 0, stream>>>(src, dst, counts, bsums, streams);
    k_aggsort<<<B_BKT, 256, 0, stream>>>(streams, counts, bsums, featb, aggb);
    k_gemm<<<GEMM_G, 256, 0, stream>>>(featb, aggb, w2t, bias, out);
}